// Round 7
// baseline (2970.654 us; speedup 1.0000x reference)
//
#include <hip/hip_runtime.h>

// Problem constants (from reference setup_inputs / NUM_POINTS)
#define BATCH 16
#define NPTS  131072
#define NCH   6
#define KSEL  1024
#define MBLK  16                 // blocks per batch
#define TPB   256
#define CHUNK (NPTS / MBLK)      // 8192 points per block
#define PPT   (CHUNK / TPB)      // 32 points per thread
#define ROT   2                  // slot rotation depth (double buffer)

// pub[BATCH][ROT][MBLK] u64 (4 KB), memset 0 before launch.
// Word: [dist_f32_bits:32][~idx:20][tag:12], tag = round k (1..1023 —
// 12-bit field never wraps; memset tag 0 never matches any polled round).
// All stores/loads RELAXED agent scope. u64 order: max dist first, then
// max ~idx = min global index — jnp.argmax first-occurrence tie-break.
// ROT=2 overwrite safety (causal): block A first overwrites slot (k&1) at
// round k+2, which requires A observed every block's round-(k+1) word; each
// block publishes k+1 only after finishing its round-k poll reads.
//
// KEY CHANGE vs R6: the occupancy limiter is now STATIC 64 KB LDS (visible
// to the compiler) + __launch_bounds__(256,2). R6 used 80 KB *dynamic* LDS:
// the backend couldn't see it, targeted ~4 waves/EU, capped itself at 112
// VGPRs and sank the xyz staging loads into the k-loop — re-streaming all
// coords from L2/L3 every round (~1.4 us/round). With a visible 64 KB LDS
// bound (2 blocks/CU -> 2 waves/EU -> 256-VGPR budget) the xr/yr/zr/dmin
// arrays (128 VGPRs) stay register-resident as designed.

extern "C" __global__ __launch_bounds__(TPB, 2)
void fps_kernel(const float* __restrict__ pts, float* __restrict__ out,
                unsigned long long* __restrict__ pub)
{
#pragma clang fp contract(off)
    __shared__ float occ_limiter[16384];     // 64 KB static, kept alive below
    __shared__ float              s_wd[TPB / 64];
    __shared__ int                s_wi[TPB / 64];
    __shared__ unsigned long long s_key[MBLK];
    __shared__ float              s_px, s_py, s_pz;

    const int b    = blockIdx.x / MBLK;
    const int m    = blockIdx.x % MBLK;
    const int tid  = threadIdx.x;
    const int base = m * CHUNK;
    const float* __restrict__ pb = pts + (size_t)b * NPTS * NCH;

    occ_limiter[tid] = 0.0f;                 // keep the LDS block allocated

    // Stage this block's xyz chunk + running min-dists in registers.
    float xr[PPT], yr[PPT], zr[PPT], dmin[PPT];
#pragma unroll
    for (int i = 0; i < PPT; ++i) {
        const float* p = pb + (size_t)(base + tid + i * TPB) * NCH;
        xr[i]   = p[0];
        yr[i]   = p[1];
        zr[i]   = p[2];
        dmin[i] = __builtin_inff();
    }

    // Selected index 0 -> output row 0.
    if (m == 0 && tid < NCH) out[(size_t)b * KSEL * NCH + tid] = pb[tid];

    // p for round 1 is point 0 (uniform scalar loads of read-only data).
    float px = pb[0], py = pb[1], pz = pb[2];

    for (int k = 1; k < KSEL; ++k) {
        // ---- dist update + thread-local argmax (first-index tie-break) ----
        float bd = -1.0f;
        int   bj = 0;
#pragma unroll
        for (int i = 0; i < PPT; ++i) {
            // Bit-exact replication of the reference's f32 op sequence:
            // each op individually rounded (RN), no FMA / no reassociation.
            float dx = __fsub_rn(xr[i], px);
            float dy = __fsub_rn(yr[i], py);
            float dz = __fsub_rn(zr[i], pz);
            float d  = __fadd_rn(__fadd_rn(__fmul_rn(dx, dx),
                                           __fmul_rn(dy, dy)),
                                 __fmul_rn(dz, dz));
            float dm = dmin[i];
            dm = (d < dm) ? d : dm;
            dmin[i] = dm;
            // j = tid + i*TPB ascends with i: strict '>' keeps first index.
            if (dm > bd) { bd = dm; bj = tid + i * TPB; }
        }

        // ---- wave(64) argmax reduce, smaller index wins ties ----
        for (int off = 32; off > 0; off >>= 1) {
            float od = __shfl_down(bd, off);
            int   oj = __shfl_down(bj, off);
            if (od > bd || (od == bd && oj < bj)) { bd = od; bj = oj; }
        }
        if ((tid & 63) == 0) {
            const int w = tid >> 6;
            s_wd[w] = bd; s_wi[w] = bj;
        }
        __syncthreads();                                   // [A]

        unsigned long long* slot =
            pub + ((size_t)b * ROT + (size_t)(k & (ROT - 1))) * MBLK;

        // ---- publish this block's tagged key (tid 0) ----
        if (tid == 0) {
            float fd = s_wd[0]; int fi = s_wi[0];
#pragma unroll
            for (int w = 1; w < TPB / 64; ++w) {
                if (s_wd[w] > fd || (s_wd[w] == fd && s_wi[w] < fi)) {
                    fd = s_wd[w]; fi = s_wi[w];
                }
            }
            const unsigned g   = (unsigned)(base + fi);
            const unsigned inv = 0xFFFFFu ^ g;             // 20-bit ~idx
            unsigned long long key =
                ((unsigned long long)__float_as_uint(fd) << 32)
                | ((unsigned long long)inv << 12)
                | (unsigned long long)(unsigned)k;         // 12-bit tag
            __hip_atomic_store(&slot[m], key, __ATOMIC_RELAXED,
                               __HIP_MEMORY_SCOPE_AGENT);
        }

        // ---- parallel poll: lane j waits for block j's word ----
        if (tid < MBLK) {
            unsigned long long v;
            do {
                v = __hip_atomic_load(&slot[tid], __ATOMIC_RELAXED,
                                      __HIP_MEMORY_SCOPE_AGENT);
            } while ((unsigned)(v & 0xFFFull) != (unsigned)k);
            s_key[tid] = v;
        }
        __syncthreads();                                   // [B]

        // ---- cross-block reduce + winner fetch (tid 0) ----
        if (tid == 0) {
            unsigned long long mx = s_key[0];
#pragma unroll
            for (int w = 1; w < MBLK; ++w) {
                if (s_key[w] > mx) mx = s_key[w];
            }
            const unsigned g = 0xFFFFFu ^ (unsigned)((mx >> 12) & 0xFFFFFull);
            const float* pp = pb + (size_t)g * NCH;  // read-only input: safe
            s_px = pp[0]; s_py = pp[1]; s_pz = pp[2];
            // Round-robin writer block emits output row k.
            if ((k & (MBLK - 1)) == m) {
                float* o = out + ((size_t)b * KSEL + k) * NCH;
#pragma unroll
                for (int c = 0; c < NCH; ++c) o[c] = pp[c];
            }
        }
        __syncthreads();                                   // [C]
        px = s_px; py = s_py; pz = s_pz;
    }
}

extern "C" void kernel_launch(void* const* d_in, const int* in_sizes, int n_in,
                              void* d_out, int out_size, void* d_ws, size_t ws_size,
                              hipStream_t stream) {
    const float* pts = (const float*)d_in[0];
    float* out = (float*)d_out;
    unsigned long long* pub = (unsigned long long*)d_ws;

    // pub[BATCH][ROT][MBLK] u64 = 4 KB; zero -> all tags 0 (never match).
    hipMemsetAsync(d_ws, 0,
                   (size_t)BATCH * ROT * MBLK * sizeof(unsigned long long),
                   stream);

    void* args[] = { (void*)&pts, (void*)&out, (void*)&pub };
    hipLaunchCooperativeKernel((const void*)fps_kernel,
                               dim3(BATCH * MBLK), dim3(TPB),
                               args, 0, stream);
}

// Round 8
// 2898.048 us; speedup vs baseline: 1.0251x; 1.0251x over previous
//
#include <hip/hip_runtime.h>

// Problem constants (from reference setup_inputs / NUM_POINTS)
#define BATCH 16
#define NPTS  131072
#define NCH   6
#define KSEL  1024
#define MBLK  16                 // blocks per batch
#define TPB   256
#define CHUNK (NPTS / MBLK)      // 8192 points per block
#define PPT   (CHUNK / TPB)      // 32 points per thread
#define ROT   2                  // slot rotation depth (double buffer)

// pub[BATCH][ROT][MBLK] u64 (4 KB), memset 0 before launch.
// Word: [dist_f32_bits:32][~idx:20][tag:12], tag = round k (1..1023 —
// 12-bit field never wraps; memset tag 0 never matches any polled round).
// All stores/loads RELAXED agent scope. u64 order: max dist first, then
// max ~idx = min global index — jnp.argmax first-occurrence tie-break.
// ROT=2 overwrite safety (causal): block A first overwrites slot (k&1) at
// round k+2, which requires A observed every block's round-(k+1) word; each
// block publishes k+1 only after finishing its round-k poll reads.
//
// R8 CHANGES vs R7 (VGPR_Count stayed 112 -> xyz loads were still being
// sunk into the k-loop and re-streamed from L2 every round):
//  1. amdgpu_waves_per_eu(2,2): max 2 waves/EU -> 256-VGPR budget, no
//     incentive to shrink to 112 for 4-wave occupancy.
//  2. Empty asm "+v" pins on xr/yr/zr after staging: the asm output is
//     opaque, so the compiler CANNOT rematerialize the loads inside the
//     loop — the 96 coord values must stay register-resident.
//  3. Barrier [C] removed: after the poll, every thread scans s_key[16]
//     itself and loads the winner row from pts (same-address broadcast
//     load), instead of tid0 fetch + LDS relay + third __syncthreads.

extern "C" __global__ __launch_bounds__(TPB)
__attribute__((amdgpu_waves_per_eu(2, 2)))
void fps_kernel(const float* __restrict__ pts, float* __restrict__ out,
                unsigned long long* __restrict__ pub)
{
#pragma clang fp contract(off)
    __shared__ float              s_wd[TPB / 64];
    __shared__ int                s_wi[TPB / 64];
    __shared__ unsigned long long s_key[MBLK];

    const int b    = blockIdx.x / MBLK;
    const int m    = blockIdx.x % MBLK;
    const int tid  = threadIdx.x;
    const int base = m * CHUNK;
    const float* __restrict__ pb = pts + (size_t)b * NPTS * NCH;

    // Stage this block's xyz chunk + running min-dists in registers.
    float xr[PPT], yr[PPT], zr[PPT], dmin[PPT];
#pragma unroll
    for (int i = 0; i < PPT; ++i) {
        const float* p = pb + (size_t)(base + tid + i * TPB) * NCH;
        xr[i]   = p[0];
        yr[i]   = p[1];
        zr[i]   = p[2];
        dmin[i] = __builtin_inff();
    }
    // Pin staged coords into VGPRs: opaque to the optimizer, so the loads
    // above cannot be sunk/rematerialized into the k-loop.
#pragma unroll
    for (int i = 0; i < PPT; ++i) {
        asm volatile("" : "+v"(xr[i]), "+v"(yr[i]), "+v"(zr[i]));
    }

    // Selected index 0 -> output row 0.
    if (m == 0 && tid < NCH) out[(size_t)b * KSEL * NCH + tid] = pb[tid];

    // p for round 1 is point 0 (uniform scalar loads of read-only data).
    float px = pb[0], py = pb[1], pz = pb[2];

    for (int k = 1; k < KSEL; ++k) {
        // ---- dist update + thread-local argmax (first-index tie-break) ----
        float bd = -1.0f;
        int   bj = 0;
#pragma unroll
        for (int i = 0; i < PPT; ++i) {
            // Bit-exact replication of the reference's f32 op sequence:
            // each op individually rounded (RN), no FMA / no reassociation.
            float dx = __fsub_rn(xr[i], px);
            float dy = __fsub_rn(yr[i], py);
            float dz = __fsub_rn(zr[i], pz);
            float d  = __fadd_rn(__fadd_rn(__fmul_rn(dx, dx),
                                           __fmul_rn(dy, dy)),
                                 __fmul_rn(dz, dz));
            float dm = dmin[i];
            dm = (d < dm) ? d : dm;
            dmin[i] = dm;
            // j = tid + i*TPB ascends with i: strict '>' keeps first index.
            if (dm > bd) { bd = dm; bj = tid + i * TPB; }
        }

        // ---- wave(64) argmax reduce, smaller index wins ties ----
        for (int off = 32; off > 0; off >>= 1) {
            float od = __shfl_down(bd, off);
            int   oj = __shfl_down(bj, off);
            if (od > bd || (od == bd && oj < bj)) { bd = od; bj = oj; }
        }
        if ((tid & 63) == 0) {
            const int w = tid >> 6;
            s_wd[w] = bd; s_wi[w] = bj;
        }
        __syncthreads();                                   // [A]

        unsigned long long* slot =
            pub + ((size_t)b * ROT + (size_t)(k & (ROT - 1))) * MBLK;

        // ---- publish this block's tagged key (tid 0) ----
        if (tid == 0) {
            float fd = s_wd[0]; int fi = s_wi[0];
#pragma unroll
            for (int w = 1; w < TPB / 64; ++w) {
                if (s_wd[w] > fd || (s_wd[w] == fd && s_wi[w] < fi)) {
                    fd = s_wd[w]; fi = s_wi[w];
                }
            }
            const unsigned g   = (unsigned)(base + fi);
            const unsigned inv = 0xFFFFFu ^ g;             // 20-bit ~idx
            unsigned long long key =
                ((unsigned long long)__float_as_uint(fd) << 32)
                | ((unsigned long long)inv << 12)
                | (unsigned long long)(unsigned)k;         // 12-bit tag
            __hip_atomic_store(&slot[m], key, __ATOMIC_RELAXED,
                               __HIP_MEMORY_SCOPE_AGENT);
        }

        // ---- parallel poll: lane j waits for block j's word ----
        if (tid < MBLK) {
            unsigned long long v;
            do {
                v = __hip_atomic_load(&slot[tid], __ATOMIC_RELAXED,
                                      __HIP_MEMORY_SCOPE_AGENT);
            } while ((unsigned)(v & 0xFFFull) != (unsigned)k);
            s_key[tid] = v;
        }
        __syncthreads();                                   // [B]

        // ---- every thread: reduce 16 keys, fetch winner row (broadcast) ----
        // s_key reads here precede next round's [A]; the poll rewrites
        // s_key only after [A] -> no race despite dropping barrier [C].
        unsigned long long mx = s_key[0];
#pragma unroll
        for (int w = 1; w < MBLK; ++w) {
            if (s_key[w] > mx) mx = s_key[w];
        }
        const unsigned g = 0xFFFFFu ^ (unsigned)((mx >> 12) & 0xFFFFFull);
        const float* pp = pb + (size_t)g * NCH;  // same addr all lanes: 1 txn
        px = pp[0]; py = pp[1]; pz = pp[2];

        // Round-robin writer block emits output row k.
        if ((k & (MBLK - 1)) == m && tid == 0) {
            float* o = out + ((size_t)b * KSEL + k) * NCH;
#pragma unroll
            for (int c = 0; c < NCH; ++c) o[c] = pp[c];
        }
    }
}

extern "C" void kernel_launch(void* const* d_in, const int* in_sizes, int n_in,
                              void* d_out, int out_size, void* d_ws, size_t ws_size,
                              hipStream_t stream) {
    const float* pts = (const float*)d_in[0];
    float* out = (float*)d_out;
    unsigned long long* pub = (unsigned long long*)d_ws;

    // pub[BATCH][ROT][MBLK] u64 = 4 KB; zero -> all tags 0 (never match).
    hipMemsetAsync(d_ws, 0,
                   (size_t)BATCH * ROT * MBLK * sizeof(unsigned long long),
                   stream);

    void* args[] = { (void*)&pts, (void*)&out, (void*)&pub };
    hipLaunchCooperativeKernel((const void*)fps_kernel,
                               dim3(BATCH * MBLK), dim3(TPB),
                               args, 0, stream);
}